// Round 1
// baseline (266.501 us; speedup 1.0000x reference)
//
#include <hip/hip_runtime.h>

// RoIMaskAlignAvg: features (B=2, C=256, H=200, W=272) fp32, rois (N=256, 5) fp32
// -> out (N, C, 14, 14) fp32.
// out[ah,aw] = (1/16) * sum over 4x4 window (stride 2) of 30x30 bilinear samples.

#define AH_ 14
#define AW_ 14
#define NS_ 30        // PH*r = PW*r = 30 sample points per axis
#define C_  256
#define H_  200
#define W_  272
#define CPB 4         // channels per block (one per wave)

__global__ __launch_bounds__(256)
void roi_mask_align_avg_kernel(const float* __restrict__ feat,
                               const float* __restrict__ rois,
                               float* __restrict__ out,
                               int N) {
    __shared__ int   sxlo[NS_], sxhi[NS_], sylo[NS_], syhi[NS_];
    __shared__ float swx0[NS_], swx1[NS_], swy0[NS_], swy1[NS_];
    __shared__ float V[CPB][NS_][NS_ + 2];   // padded row stride 32

    const int blocks_per_roi = C_ / CPB;     // 64
    const int n   = blockIdx.x / blocks_per_roi;
    const int cg  = blockIdx.x - n * blocks_per_roi;
    const int c0  = cg * CPB;

    const int tid  = threadIdx.x;
    const int wave = tid >> 6;
    const int lane = tid & 63;

    // --- per-roi geometry (replicates reference fp op order) ---
    const float r0  = rois[n * 5 + 0];
    const float x1s = rois[n * 5 + 1] * 0.25f;
    const float y1s = rois[n * 5 + 2] * 0.25f;
    const float x2s = rois[n * 5 + 3] * 0.25f;
    const float y2s = rois[n * 5 + 4] * 0.25f;
    const int   b   = (int)r0;

    const float cx = 0.5f * (x1s + x2s), cy = 0.5f * (y1s + y2s);
    const float hw = 0.5f * (x2s - x1s), hh = 0.5f * (y2s - y1s);
    const float x1 = cx - hw, x2 = cx + hw;
    const float y1 = cy - hh, y2 = cy + hh;
    const float roi_w = fmaxf(x2 - x1, 1.0f);
    const float roi_h = fmaxf(y2 - y1, 1.0f);
    // bin_w / r  with PW = PH = 15, r = 2
    const float sub_w = roi_w * (1.0f / 15.0f) * 0.5f;
    const float sub_h = roi_h * (1.0f / 15.0f) * 0.5f;

    // --- sample metadata into LDS (x: threads 0..29, y: threads 64..93) ---
    if (tid < NS_) {
        const int i = tid;
        const float sx = x1 + ((float)i + 0.5f) * sub_w;
        const bool  v  = (sx > -1.0f) && (sx < (float)W_);
        const float cc = fminf(fmaxf(sx, 0.0f), (float)(W_ - 1));
        const float lo = floorf(cc);
        const int  ilo = (int)lo;
        const int  ihi = min(ilo + 1, W_ - 1);
        const float fr = cc - lo;
        const float vm = v ? 1.0f : 0.0f;
        sxlo[i] = ilo; sxhi[i] = ihi;
        swx0[i] = (1.0f - fr) * vm; swx1[i] = fr * vm;
    } else if (tid >= 64 && tid < 64 + NS_) {
        const int i = tid - 64;
        const float sy = y1 + ((float)i + 0.5f) * sub_h;
        const bool  v  = (sy > -1.0f) && (sy < (float)H_);
        const float cc = fminf(fmaxf(sy, 0.0f), (float)(H_ - 1));
        const float lo = floorf(cc);
        const int  ilo = (int)lo;
        const int  ihi = min(ilo + 1, H_ - 1);
        const float fr = cc - lo;
        const float vm = v ? 1.0f : 0.0f;
        sylo[i] = ilo; syhi[i] = ihi;
        swy0[i] = (1.0f - fr) * vm; swy1[i] = fr * vm;
    }
    __syncthreads();

    // --- gather 30x30 bilinear samples for this wave's channel ---
    const int c = c0 + wave;
    const float* __restrict__ fp = feat + ((size_t)b * C_ + c) * (size_t)(H_ * W_);

    for (int s = lane; s < NS_ * NS_; s += 64) {
        const int iy = s / NS_;
        const int ix = s - iy * NS_;
        const int yl = sylo[iy], yh = syhi[iy];
        const int xl = sxlo[ix], xh = sxhi[ix];
        const float wy0 = swy0[iy], wy1 = swy1[iy];
        const float wx0 = swx0[ix], wx1 = swx1[ix];
        const float* r0p = fp + (size_t)yl * W_;
        const float* r1p = fp + (size_t)yh * W_;
        const float v = r0p[xl] * (wy0 * wx0) + r0p[xh] * (wy0 * wx1)
                      + r1p[xl] * (wy1 * wx0) + r1p[xh] * (wy1 * wx1);
        V[wave][iy][ix] = v;
    }
    __syncthreads();

    // --- pool: 4x4 window, stride 2, scale 1/16 ---
    float* __restrict__ op = out + ((size_t)n * C_ + c) * (AH_ * AW_);
    for (int o = lane; o < AH_ * AW_; o += 64) {
        const int ah = o / AW_;
        const int aw = o - ah * AW_;
        float sum = 0.0f;
        #pragma unroll
        for (int dy = 0; dy < 4; ++dy) {
            const float* vr = &V[wave][2 * ah + dy][2 * aw];
            sum += vr[0] + vr[1] + vr[2] + vr[3];
        }
        op[o] = sum * (1.0f / 16.0f);
    }
}

extern "C" void kernel_launch(void* const* d_in, const int* in_sizes, int n_in,
                              void* d_out, int out_size, void* d_ws, size_t ws_size,
                              hipStream_t stream) {
    const float* feat = (const float*)d_in[0];
    const float* rois = (const float*)d_in[1];
    float* out = (float*)d_out;
    const int N = in_sizes[1] / 5;           // 256
    const int grid = N * (C_ / CPB);         // 16384 blocks
    roi_mask_align_avg_kernel<<<grid, 256, 0, stream>>>(feat, rois, out, N);
}

// Round 2
// 254.537 us; speedup vs baseline: 1.0470x; 1.0470x over previous
//
#include <hip/hip_runtime.h>

// RoIMaskAlignAvg: features (B=2, C=256, H=200, W=272) fp32, rois (N=256, 5) fp32
// -> out (N, C, 14, 14) fp32.
// out[ah,aw] = (1/16) * sum over 4x4 window (stride 2) of a 30x30 bilinear
// sample grid. Separable pooling: horizontal 4-sums then vertical 4-sums.

#define AH_ 14
#define AW_ 14
#define NS_ 30        // 30 sample points per axis
#define C_  256
#define H_  200
#define W_  272
#define CPB 4         // channels per block (one per wave)
#define VS_ 33        // V row stride (odd -> spreads banks)
#define HS_ 15        // Hsum row stride (odd)

__global__ __launch_bounds__(256)
void roi_mask_align_avg_kernel(const float* __restrict__ feat,
                               const float* __restrict__ rois,
                               float* __restrict__ out) {
    __shared__ float V[CPB][NS_ * VS_];    // 4 * 990 * 4B = 15.8 KB
    __shared__ float Hs[CPB][NS_ * HS_];   // 4 * 450 * 4B = 7.2 KB

    // --- XCD-aware swizzle: XCD (p%8) streams one 4-channel slice over all rois.
    // physical p = xcd + 8*(n + 256*cgi);  cg = 8*cgi + xcd
    const int p   = blockIdx.x;
    const int xcd = p & 7;
    const int q   = p >> 3;
    const int n   = q & 255;
    const int cgi = q >> 8;            // 0..7
    const int cg  = cgi * 8 + xcd;     // 0..63
    const int c0  = cg * CPB;

    const int tid  = threadIdx.x;
    const int wave = tid >> 6;
    const int lane = tid & 63;
    const int ix   = lane & 31;        // sample x index (0..29 used)
    const int half = lane >> 5;        // which of 2 rows this pass

    // --- per-roi geometry (replicates reference fp op order) ---
    const float r0f = rois[n * 5 + 0];
    const float x1s = rois[n * 5 + 1] * 0.25f;
    const float y1s = rois[n * 5 + 2] * 0.25f;
    const float x2s = rois[n * 5 + 3] * 0.25f;
    const float y2s = rois[n * 5 + 4] * 0.25f;
    const int   b   = (int)r0f;

    const float cx = 0.5f * (x1s + x2s), cy = 0.5f * (y1s + y2s);
    const float hw = 0.5f * (x2s - x1s), hh = 0.5f * (y2s - y1s);
    const float x1 = cx - hw, x2 = cx + hw;
    const float y1 = cy - hh, y2 = cy + hh;
    const float roi_w = fmaxf(x2 - x1, 1.0f);
    const float roi_h = fmaxf(y2 - y1, 1.0f);
    const float sub_w = roi_w * (1.0f / 15.0f) * 0.5f;   // bin_w / r
    const float sub_h = roi_h * (1.0f / 15.0f) * 0.5f;

    // --- x-direction sample metadata: registers, computed once per lane ---
    const float sx  = x1 + ((float)ix + 0.5f) * sub_w;
    const bool  vx_ = (sx > -1.0f) && (sx < (float)W_);
    const float ccx = fminf(fmaxf(sx, 0.0f), (float)(W_ - 1));
    const float lox = floorf(ccx);
    const int   xl  = (int)lox;
    const int   xh  = min(xl + 1, W_ - 1);
    const float fx  = ccx - lox;
    const float vmx = vx_ ? 1.0f : 0.0f;
    const float wx0 = (1.0f - fx) * vmx;
    const float wx1 = fx * vmx;

    const int c = c0 + wave;
    const float* __restrict__ fp = feat + ((size_t)b * C_ + c) * (size_t)(H_ * W_);
    float* __restrict__ Vw = V[wave];

    // --- gather: 15 passes, 2 rows per pass (lanes 0..29 row iy, 32..61 row iy+1)
    #pragma unroll 5
    for (int ps = 0; ps < 15; ++ps) {
        const int   iy  = 2 * ps + half;
        const float sy  = y1 + ((float)iy + 0.5f) * sub_h;
        const bool  vy_ = (sy > -1.0f) && (sy < (float)H_);
        const float ccy = fminf(fmaxf(sy, 0.0f), (float)(H_ - 1));
        const float loy = floorf(ccy);
        const int   yl  = (int)loy;
        const int   yh  = min(yl + 1, H_ - 1);
        const float fy  = ccy - loy;
        const float vmy = vy_ ? 1.0f : 0.0f;
        const float wy0 = (1.0f - fy) * vmy;
        const float wy1 = fy * vmy;

        const float* r0p = fp + yl * W_;
        const float* r1p = fp + yh * W_;
        const float v = r0p[xl] * (wy0 * wx0) + r0p[xh] * (wy0 * wx1)
                      + r1p[xl] * (wy1 * wx0) + r1p[xh] * (wy1 * wx1);
        if (ix < NS_) Vw[iy * VS_ + ix] = v;
    }
    __syncthreads();

    // --- stage 2: horizontal 4-sums  Hs[iy][aw] = sum_k V[iy][2aw+k] ---
    float* __restrict__ Hw = Hs[wave];
    for (int o = lane; o < NS_ * AW_; o += 64) {      // 420 tasks
        const int iy = o / AW_;
        const int aw = o - iy * AW_;
        const float* vr = Vw + iy * VS_ + 2 * aw;
        Hw[iy * HS_ + aw] = vr[0] + vr[1] + vr[2] + vr[3];
    }
    __syncthreads();

    // --- stage 3: vertical 4-sums, scale 1/16, write out ---
    float* __restrict__ op = out + ((size_t)n * C_ + c) * (AH_ * AW_);
    for (int o = lane; o < AH_ * AW_; o += 64) {      // 196 tasks
        const int ah = o / AW_;
        const int aw = o - ah * AW_;
        const float* hr = Hw + (2 * ah) * HS_ + aw;
        op[o] = (hr[0] + hr[HS_] + hr[2 * HS_] + hr[3 * HS_]) * (1.0f / 16.0f);
    }
}

extern "C" void kernel_launch(void* const* d_in, const int* in_sizes, int n_in,
                              void* d_out, int out_size, void* d_ws, size_t ws_size,
                              hipStream_t stream) {
    const float* feat = (const float*)d_in[0];
    const float* rois = (const float*)d_in[1];
    float* out = (float*)d_out;
    const int grid = 256 * (C_ / CPB);   // 16384 blocks
    roi_mask_align_avg_kernel<<<grid, 256, 0, stream>>>(feat, rois, out);
}